// Round 4
// baseline (607.467 us; speedup 1.0000x reference)
//
#include <hip/hip_runtime.h>

typedef _Float16 half8  __attribute__((ext_vector_type(8)));
typedef _Float16 half4v __attribute__((ext_vector_type(4)));
typedef _Float16 half2v __attribute__((ext_vector_type(2)));
typedef float    floatx4 __attribute__((ext_vector_type(4)));
typedef float    f4v     __attribute__((ext_vector_type(4)));

#define NND 8192
#define PA  40   // LDS pitch (f16) for small-GEMM tiles
#define PT  128  // LDS pitch (f16) for transpose tile (256B rows, XOR-swizzled chunks)

__device__ __forceinline__ int swzk(int m, int k) { return k ^ (((m >> 3) & 3) << 3); }
// 16B-chunk swizzle for the degT transpose tile
__device__ __forceinline__ int swzT(int row, int chunk) { return chunk ^ ((row >> 2) & 15); }

#define GLOAD16(gp, lp) __builtin_amdgcn_global_load_lds(                        \
    (const __attribute__((address_space(1))) void*)(gp),                         \
    (__attribute__((address_space(3))) void*)(lp), 16, 0, 0)

#define VMCNT0() asm volatile("s_waitcnt vmcnt(0)" ::: "memory")

__device__ __forceinline__ float dis_of(float d) { return d > 0.f ? 1.f / sqrtf(d) : 0.f; }

// ---- fused: deg[j] += sum_i relu(attn[i,j]);  Wh[j][i] = f16(relu(attn[i,j])) ----
__global__ __launch_bounds__(256) void k_degT(const float* __restrict__ A,
                                              _Float16* __restrict__ Wh,
                                              float* __restrict__ deg) {
    __shared__ _Float16 T[128 * PT];
    __shared__ float sdeg[8 * 128];
    int t  = threadIdx.x;
    int j0 = blockIdx.x * 128, i0 = blockIdx.y * 128;
    int c = t & 31;      // j4-group: cols j0 + 4c .. 4c+3
    int g = t >> 5;      // 0..7: row group

    f4v s = {0.f, 0.f, 0.f, 0.f};
    #pragma unroll
    for (int p = 0; p < 2; ++p) {                       // 2 passes x 64 rows
        int rb = 64 * p + 8 * g;                        // 8 consecutive rows per thread
        f4v v[8];
        #pragma unroll
        for (int rr = 0; rr < 8; ++rr)
            v[rr] = *(const f4v*)(A + (size_t)(i0 + rb + rr) * NND + j0 + 4 * c);
        #pragma unroll
        for (int rr = 0; rr < 8; ++rr)
            #pragma unroll
            for (int u = 0; u < 4; ++u) v[rr][u] = fmaxf(v[rr][u], 0.f);
        #pragma unroll
        for (int u = 0; u < 4; ++u) {
            half8 hv;
            #pragma unroll
            for (int rr = 0; rr < 8; ++rr) { hv[rr] = (_Float16)v[rr][u]; s[u] += v[rr][u]; }
            int row = 4 * c + u;
            int chunk = 8 * p + g;                       // 16B chunk along i
            *(half8*)(&T[row * PT + swzT(row, chunk) * 8]) = hv;
        }
    }
    *(f4v*)(&sdeg[g * 128 + 4 * c]) = s;
    __syncthreads();

    if (t < 128) {
        float d = 0.f;
        #pragma unroll
        for (int g2 = 0; g2 < 8; ++g2) d += sdeg[g2 * 128 + t];
        atomicAdd(&deg[j0 + t], d);
    }

    #pragma unroll
    for (int p = 0; p < 8; ++p) {                       // write phase: coalesced along i
        int j  = 16 * p + (t >> 4);
        int mc = t & 15;                                 // logical chunk = i/8
        half8 hv = *(const half8*)(&T[j * PT + swzT(j, mc) * 8]);
        *(half8*)(Wh + (size_t)(j0 + j) * NND + i0 + mc * 8) = hv;
    }
}

// ------------- small GEMM: outT[n][i] = f16( dis(deg[i]) * (A@B)[i,n] * out_scale ) -------------
template <typename AT>
__global__ __launch_bounds__(256) void k_mm_small(
    const AT* __restrict__ Abase, const int* __restrict__ gather,
    const float* __restrict__ B, int NB,
    _Float16* __restrict__ outT, const float* __restrict__ deg, float out_scale) {

    __shared__ _Float16 As[128 * PA];
    __shared__ _Float16 Bs[64 * PA];

    int t  = threadIdx.x;
    int i0 = blockIdx.x * 128;
    int n0 = blockIdx.y * 64;

    int am = t & 127, akh = t >> 7;
    int row = i0 + am;
    if (gather) row = gather[row];
    const AT* arow = Abase + (size_t)row * 256;

    int tp = t & 15, kp = t >> 4;

    int lane = t & 63, w = t >> 6;
    int wm = w & 1, wn = w >> 1;
    int lm = lane & 15, q = lane >> 4;

    floatx4 acc[4][2];
    #pragma unroll
    for (int a = 0; a < 4; ++a)
        #pragma unroll
        for (int b = 0; b < 2; ++b) acc[a][b] = (floatx4){0.f, 0.f, 0.f, 0.f};

    for (int ks = 0; ks < 8; ++ks) {
        int c0 = ks * 32;

        half8 av[2];
        if constexpr (sizeof(AT) == 4) {
            #pragma unroll
            for (int cc = 0; cc < 2; ++cc) {
                f4v v0 = *(const f4v*)(arow + c0 + akh * 16 + cc * 8);
                f4v v1 = *(const f4v*)(arow + c0 + akh * 16 + cc * 8 + 4);
                half8 hv;
                #pragma unroll
                for (int e = 0; e < 4; ++e) {
                    hv[e]     = (_Float16)(16.f * v0[e]);
                    hv[4 + e] = (_Float16)(16.f * v1[e]);
                }
                av[cc] = hv;
            }
        } else {
            av[0] = *(const half8*)(arow + c0 + akh * 16);
            av[1] = *(const half8*)(arow + c0 + akh * 16 + 8);
        }

        const float* bp = B + (size_t)(c0 + 2 * kp) * NB + n0 + 4 * tp;
        f4v r0 = *(const f4v*)bp;
        f4v r1 = *(const f4v*)(bp + NB);

        __syncthreads();
        #pragma unroll
        for (int cc = 0; cc < 2; ++cc) {
            int k = akh * 16 + cc * 8;
            *(half8*)(&As[am * PA + swzk(am, k)]) = av[cc];
        }
        #pragma unroll
        for (int u = 0; u < 4; ++u) {
            int n = 4 * tp + u;
            half2v p = {(_Float16)r0[u], (_Float16)r1[u]};
            *(half2v*)(&Bs[n * PA + swzk(n, 2 * kp)]) = p;
        }
        __syncthreads();

        half8 af[4], bf[2];
        #pragma unroll
        for (int mt = 0; mt < 4; ++mt) {
            int m = wm * 64 + mt * 16 + lm;
            af[mt] = *(const half8*)(&As[m * PA + swzk(m, q * 8)]);
        }
        #pragma unroll
        for (int nt = 0; nt < 2; ++nt) {
            int n = wn * 32 + nt * 16 + lm;
            bf[nt] = *(const half8*)(&Bs[n * PA + swzk(n, q * 8)]);
        }
        #pragma unroll
        for (int mt = 0; mt < 4; ++mt)
            #pragma unroll
            for (int nt = 0; nt < 2; ++nt)
                acc[mt][nt] = __builtin_amdgcn_mfma_f32_16x16x32_f16(af[mt], bf[nt], acc[mt][nt], 0, 0, 0);
    }

    #pragma unroll
    for (int mt = 0; mt < 4; ++mt) {
        int ib = i0 + wm * 64 + mt * 16 + q * 4;
        float di[4];
        #pragma unroll
        for (int r = 0; r < 4; ++r) di[r] = dis_of(deg[ib + r]) * out_scale;
        #pragma unroll
        for (int nt = 0; nt < 2; ++nt) {
            int n = n0 + wn * 32 + nt * 16 + lm;
            #pragma unroll
            for (int r = 0; r < 4; ++r) {
                float v = acc[mt][nt][r] * di[r];
                outT[(size_t)n * NND + ib + r] = (_Float16)v;
            }
        }
    }
}

// ------------- big GEMM (2-phase dbuf, conflict-free LDS via source-side swizzle) -------------
// LDS stays LINEAR (global_load_lds). Global source chunk is pre-permuted
// (c_g = c ^ ((row>>1)&3)); reads apply the same XOR -> 2-way banks (free).
template <int BN, int ZSTEPS>
__global__ __launch_bounds__(256) void k_mm_big(
    const _Float16* __restrict__ Wh, const _Float16* __restrict__ Bt, float* __restrict__ Cp) {

    __shared__ __align__(16) _Float16 As[2 * 128 * 32];
    __shared__ __align__(16) _Float16 Bs[2 * 128 * 32];

    int t = threadIdx.x;
    int bx = blockIdx.x;
    bx = (bx & 7) * 8 + (bx >> 3);        // XCD-aware swizzle (64 tiles, bijective)
    int j0 = bx * 128;
    int n0 = blockIdx.y * 128;
    size_t i_begin = (size_t)blockIdx.z * (ZSTEPS * 32);
    float* C = Cp + (size_t)blockIdx.z * (size_t)NND * BN;

    int lane = t & 63, w = t >> 6;
    int wm = w & 1, wn = w >> 1;
    int lm = lane & 15, q = lane >> 4;
    int qa = q ^ ((lm >> 1) & 3);         // swizzled 16B-chunk for LDS reads

    // staging: lane -> (row = u*16 + (lane>>2), slot-chunk = lane&3);
    // global chunk fetched = slot-chunk ^ ((row>>1)&3) = (lane&3) ^ ((lane>>3)&3)
    int srow = lane >> 2;
    int scol = ((lane & 3) ^ ((lane >> 3) & 3)) * 8;
    const _Float16* aS0 = Wh + (size_t)(j0 + w * 16 + srow) * NND + i_begin + scol;
    const _Float16* aS1 = aS0 + (size_t)64 * NND;
    const _Float16* bS0 = Bt + (size_t)(n0 + w * 16 + srow) * NND + i_begin + scol;
    const _Float16* bS1 = bS0 + (size_t)64 * NND;

    char* aLb = (char*)As + w * 1024;     // + buf*8192, + 4096 for second issue
    char* bLb = (char*)Bs + w * 1024;

    floatx4 acc[4][4];
    #pragma unroll
    for (int a = 0; a < 4; ++a)
        #pragma unroll
        for (int b = 0; b < 4; ++b) acc[a][b] = (floatx4){0.f, 0.f, 0.f, 0.f};

    // prologue: stage tile 0 into buf 0
    GLOAD16(aS0, aLb);
    GLOAD16(aS1, aLb + 4096);
    GLOAD16(bS0, bLb);
    GLOAD16(bS1, bLb + 4096);
    VMCNT0();
    __builtin_amdgcn_s_barrier();

    for (int ks = 0; ks < ZSTEPS; ++ks) {
        int cur = ks & 1;
        const _Float16* Ab = As + cur * 4096;
        const _Float16* Bb = Bs + cur * 4096;

        if (ks < ZSTEPS - 1) {                // prefetch next tile into other buf
            int ko = (ks + 1) * 32;
            char* aL = aLb + (cur ^ 1) * 8192;
            char* bL = bLb + (cur ^ 1) * 8192;
            GLOAD16(aS0 + ko, aL);
            GLOAD16(aS1 + ko, aL + 4096);
            GLOAD16(bS0 + ko, bL);
            GLOAD16(bS1 + ko, bL + 4096);
        }

        half8 af[4], bf[4];
        #pragma unroll
        for (int mt = 0; mt < 4; ++mt) {
            int m = wm * 64 + mt * 16 + lm;
            af[mt] = *(const half8*)(&Ab[m * 32 + qa * 8]);
        }
        #pragma unroll
        for (int nt = 0; nt < 4; ++nt) {
            int n = wn * 64 + nt * 16 + lm;
            bf[nt] = *(const half8*)(&Bb[n * 32 + qa * 8]);
        }
        __builtin_amdgcn_s_setprio(1);
        #pragma unroll
        for (int mt = 0; mt < 4; ++mt)
            #pragma unroll
            for (int nt = 0; nt < 4; ++nt)
                acc[mt][nt] = __builtin_amdgcn_mfma_f32_16x16x32_f16(af[mt], bf[nt], acc[mt][nt], 0, 0, 0);
        __builtin_amdgcn_s_setprio(0);

        VMCNT0();
        __builtin_amdgcn_s_barrier();
    }

    #pragma unroll
    for (int mt = 0; mt < 4; ++mt) {
        int rb = j0 + wm * 64 + mt * 16 + q * 4;
        #pragma unroll
        for (int nt = 0; nt < 4; ++nt) {
            int col = n0 + wn * 64 + nt * 16 + lm;
            #pragma unroll
            for (int r = 0; r < 4; ++r)
                C[(size_t)(rb + r) * BN + col] = acc[mt][nt][r];
        }
    }
}

// ------------- epilogue: reduce NZ z-partials; out = f16( (dis_j*S/1024 + bias[n]) [relu] * 64 ) ----
template <int NSH, bool RELU, int NZ>
__global__ __launch_bounds__(256) void k_finalize(const float* __restrict__ Cp, const float* __restrict__ deg,
                                                  const float* __restrict__ bias, _Float16* __restrict__ out) {
    int idx4 = (blockIdx.x * 256 + threadIdx.x) * 4;
    f4v v = {0.f, 0.f, 0.f, 0.f};
    #pragma unroll
    for (int z = 0; z < NZ; ++z) {
        f4v p = *(const f4v*)(Cp + (size_t)z * (NND << NSH) + idx4);
        #pragma unroll
        for (int r = 0; r < 4; ++r) v[r] += p[r];
    }
    int j  = idx4 >> NSH;
    int n0 = idx4 & ((1 << NSH) - 1);
    float dj = dis_of(deg[j]) * (1.f / 1024.f);
    f4v b4 = *(const f4v*)(bias + n0);
    half4v o;
    #pragma unroll
    for (int r = 0; r < 4; ++r) {
        float x = v[r] * dj + b4[r];
        if (RELU) x = fmaxf(x, 0.f);
        o[r] = (_Float16)(x * 64.f);
    }
    *(half4v*)(out + idx4) = o;
}

// ------------- edge scores: 16 lanes per edge, 4 edges per group, zh rows are 256B -------------
__global__ __launch_bounds__(256) void k_edges(const _Float16* __restrict__ zh, const int* __restrict__ ei,
                                               float* __restrict__ out, int npred) {
    int g0 = ((blockIdx.x * 256 + threadIdx.x) >> 4) * 4;
    int l = threadIdx.x & 15;
    #pragma unroll
    for (int e = 0; e < 4; ++e) {
        int g = g0 + e;
        if (g >= npred) return;
        int a = ei[g], b = ei[npred + g];
        half8 za = *(const half8*)(zh + (size_t)a * 128 + l * 8);
        half8 zb = *(const half8*)(zh + (size_t)b * 128 + l * 8);
        float s = 0.f;
        #pragma unroll
        for (int u = 0; u < 4; ++u) {
            half2v a2 = {za[2 * u], za[2 * u + 1]};
            half2v b2 = {zb[2 * u], zb[2 * u + 1]};
            s = __builtin_amdgcn_fdot2(a2, b2, s, false);
        }
        s += __shfl_xor(s, 1);
        s += __shfl_xor(s, 2);
        s += __shfl_xor(s, 4);
        s += __shfl_xor(s, 8);
        if (l == 0) out[g] = s * (1.f / 4096.f);
    }
}

extern "C" void kernel_launch(void* const* d_in, const int* in_sizes, int n_in,
                              void* d_out, int out_size, void* d_ws, size_t ws_size,
                              hipStream_t stream) {
    const int*   nodes = (const int*)d_in[0];
    const float* attn  = (const float*)d_in[1];
    const int*   eidx  = (const int*)d_in[2];
    const float* emb   = (const float*)d_in[3];
    const float* W1    = (const float*)d_in[4];
    const float* b1    = (const float*)d_in[5];
    const float* W2    = (const float*)d_in[6];
    const float* b2    = (const float*)d_in[7];
    float* out = (float*)d_out;
    int npred = in_sizes[2] / 2;

    char* ws = (char*)d_ws;
    float*    deg = (float*)(ws);                         // 32 KB
    _Float16* Wh  = (_Float16*)(ws + 0x10000);            // 128 MB f16 [8192][8192]
    float*    C1p = (float*)(ws + 0x8010000);             // 32 MB  fp32 z4 x [8192][256]
    float*    C2p = (float*)(ws + 0xC010000);             // 32 MB  fp32 z8 x [8192][128]
    _Float16* M1p = (_Float16*)(ws + 0xE010000);          // 4 MB   f16 [256][8192]
    _Float16* h   = (_Float16*)(ws + 0xE410000);          // 4 MB   f16 [8192][256]
    _Float16* M2p = (_Float16*)(ws + 0xE810000);          // 2 MB   f16 [128][8192]
    _Float16* zh  = (_Float16*)(ws + 0xEA10000);          // 2 MB   f16 [8192][128]

    hipMemsetAsync(deg, 0, 8192 * sizeof(float), stream);

    k_degT<<<dim3(64, 64), 256, 0, stream>>>(attn, Wh, deg);

    // M1p[n][i] = f16(1024 * dis_i * (x@W1)[i,n]);  A staged as 16*x, so out_scale = 64
    k_mm_small<float><<<dim3(64, 4), 256, 0, stream>>>(emb, nodes, W1, 256, M1p, deg, 64.f);
    k_mm_big<256, 64><<<dim3(64, 2, 4), 256, 0, stream>>>(Wh, M1p, C1p);
    // h = relu(dis_j*sum(C1p)/1024 + b1) * 64
    k_finalize<8, true, 4><<<2048, 256, 0, stream>>>(C1p, deg, b1, h);
    // M2p[n][i] = f16(1024 * dis_i * (h_true@W2)[i,n]); h is 64*h_true, so out_scale = 16
    k_mm_small<_Float16><<<dim3(64, 2), 256, 0, stream>>>(h, nullptr, W2, 128, M2p, deg, 16.f);
    k_mm_big<128, 32><<<dim3(64, 1, 8), 256, 0, stream>>>(Wh, M2p, C2p);
    // zh = (dis_j*sum(C2p)/1024 + b2) * 64
    k_finalize<7, false, 8><<<1024, 256, 0, stream>>>(C2p, deg, b2, zh);

    k_edges<<<(npred + 63) / 64, 256, 0, stream>>>(zh, eidx, out, npred);
}

// Round 5
// 588.228 us; speedup vs baseline: 1.0327x; 1.0327x over previous
//
#include <hip/hip_runtime.h>

typedef _Float16 half8  __attribute__((ext_vector_type(8)));
typedef _Float16 half4v __attribute__((ext_vector_type(4)));
typedef _Float16 half2v __attribute__((ext_vector_type(2)));
typedef float    floatx4 __attribute__((ext_vector_type(4)));
typedef float    f4v     __attribute__((ext_vector_type(4)));

#define NND 8192
#define PA  40   // LDS pitch (f16) for small-GEMM tiles
#define PT  128  // LDS pitch (f16) for transpose tile (256B rows, XOR-swizzled chunks)

__device__ __forceinline__ int swzk(int m, int k) { return k ^ (((m >> 3) & 3) << 3); }
// 16B-chunk swizzle for the degT transpose tile
__device__ __forceinline__ int swzT(int row, int chunk) { return chunk ^ ((row >> 2) & 15); }

#define GLOAD16(gp, lp) __builtin_amdgcn_global_load_lds(                        \
    (const __attribute__((address_space(1))) void*)(gp),                         \
    (__attribute__((address_space(3))) void*)(lp), 16, 0, 0)

#define VMCNT0() asm volatile("s_waitcnt vmcnt(0)" ::: "memory")

__device__ __forceinline__ float dis_of(float d) { return d > 0.f ? 1.f / sqrtf(d) : 0.f; }

// ---- fused: deg[j] += sum_i relu(attn[i,j]);  Wh[j][i] = f16(relu(attn[i,j])) ----
__global__ __launch_bounds__(256) void k_degT(const float* __restrict__ A,
                                              _Float16* __restrict__ Wh,
                                              float* __restrict__ deg) {
    __shared__ _Float16 T[128 * PT];
    __shared__ float sdeg[8 * 128];
    int t  = threadIdx.x;
    int j0 = blockIdx.x * 128, i0 = blockIdx.y * 128;
    int c = t & 31;      // j4-group: cols j0 + 4c .. 4c+3
    int g = t >> 5;      // 0..7: row group

    f4v s = {0.f, 0.f, 0.f, 0.f};
    #pragma unroll
    for (int p = 0; p < 2; ++p) {                       // 2 passes x 64 rows
        int rb = 64 * p + 8 * g;                        // 8 consecutive rows per thread
        f4v v[8];
        #pragma unroll
        for (int rr = 0; rr < 8; ++rr)
            v[rr] = *(const f4v*)(A + (size_t)(i0 + rb + rr) * NND + j0 + 4 * c);
        #pragma unroll
        for (int rr = 0; rr < 8; ++rr)
            #pragma unroll
            for (int u = 0; u < 4; ++u) v[rr][u] = fmaxf(v[rr][u], 0.f);
        #pragma unroll
        for (int u = 0; u < 4; ++u) {
            half8 hv;
            #pragma unroll
            for (int rr = 0; rr < 8; ++rr) { hv[rr] = (_Float16)v[rr][u]; s[u] += v[rr][u]; }
            int row = 4 * c + u;
            int chunk = 8 * p + g;                       // 16B chunk along i
            *(half8*)(&T[row * PT + swzT(row, chunk) * 8]) = hv;
        }
    }
    *(f4v*)(&sdeg[g * 128 + 4 * c]) = s;
    __syncthreads();

    if (t < 128) {
        float d = 0.f;
        #pragma unroll
        for (int g2 = 0; g2 < 8; ++g2) d += sdeg[g2 * 128 + t];
        atomicAdd(&deg[j0 + t], d);
    }

    #pragma unroll
    for (int p = 0; p < 8; ++p) {                       // write phase: coalesced along i
        int j  = 16 * p + (t >> 4);
        int mc = t & 15;                                 // logical chunk = i/8
        half8 hv = *(const half8*)(&T[j * PT + swzT(j, mc) * 8]);
        *(half8*)(Wh + (size_t)(j0 + j) * NND + i0 + mc * 8) = hv;
    }
}

// ------------- small GEMM: outT[n][i] = f16( dis(deg[i]) * (A@B)[i,n] * out_scale ) -------------
template <typename AT>
__global__ __launch_bounds__(256) void k_mm_small(
    const AT* __restrict__ Abase, const int* __restrict__ gather,
    const float* __restrict__ B, int NB,
    _Float16* __restrict__ outT, const float* __restrict__ deg, float out_scale) {

    __shared__ _Float16 As[128 * PA];
    __shared__ _Float16 Bs[64 * PA];

    int t  = threadIdx.x;
    int i0 = blockIdx.x * 128;
    int n0 = blockIdx.y * 64;

    int am = t & 127, akh = t >> 7;
    int row = i0 + am;
    if (gather) row = gather[row];
    const AT* arow = Abase + (size_t)row * 256;

    int tp = t & 15, kp = t >> 4;

    int lane = t & 63, w = t >> 6;
    int wm = w & 1, wn = w >> 1;
    int lm = lane & 15, q = lane >> 4;

    floatx4 acc[4][2];
    #pragma unroll
    for (int a = 0; a < 4; ++a)
        #pragma unroll
        for (int b = 0; b < 2; ++b) acc[a][b] = (floatx4){0.f, 0.f, 0.f, 0.f};

    for (int ks = 0; ks < 8; ++ks) {
        int c0 = ks * 32;

        half8 av[2];
        if constexpr (sizeof(AT) == 4) {
            #pragma unroll
            for (int cc = 0; cc < 2; ++cc) {
                f4v v0 = *(const f4v*)(arow + c0 + akh * 16 + cc * 8);
                f4v v1 = *(const f4v*)(arow + c0 + akh * 16 + cc * 8 + 4);
                half8 hv;
                #pragma unroll
                for (int e = 0; e < 4; ++e) {
                    hv[e]     = (_Float16)(16.f * v0[e]);
                    hv[4 + e] = (_Float16)(16.f * v1[e]);
                }
                av[cc] = hv;
            }
        } else {
            av[0] = *(const half8*)(arow + c0 + akh * 16);
            av[1] = *(const half8*)(arow + c0 + akh * 16 + 8);
        }

        const float* bp = B + (size_t)(c0 + 2 * kp) * NB + n0 + 4 * tp;
        f4v r0 = *(const f4v*)bp;
        f4v r1 = *(const f4v*)(bp + NB);

        __syncthreads();
        #pragma unroll
        for (int cc = 0; cc < 2; ++cc) {
            int k = akh * 16 + cc * 8;
            *(half8*)(&As[am * PA + swzk(am, k)]) = av[cc];
        }
        #pragma unroll
        for (int u = 0; u < 4; ++u) {
            int n = 4 * tp + u;
            half2v p = {(_Float16)r0[u], (_Float16)r1[u]};
            *(half2v*)(&Bs[n * PA + swzk(n, 2 * kp)]) = p;
        }
        __syncthreads();

        half8 af[4], bf[2];
        #pragma unroll
        for (int mt = 0; mt < 4; ++mt) {
            int m = wm * 64 + mt * 16 + lm;
            af[mt] = *(const half8*)(&As[m * PA + swzk(m, q * 8)]);
        }
        #pragma unroll
        for (int nt = 0; nt < 2; ++nt) {
            int n = wn * 32 + nt * 16 + lm;
            bf[nt] = *(const half8*)(&Bs[n * PA + swzk(n, q * 8)]);
        }
        #pragma unroll
        for (int mt = 0; mt < 4; ++mt)
            #pragma unroll
            for (int nt = 0; nt < 2; ++nt)
                acc[mt][nt] = __builtin_amdgcn_mfma_f32_16x16x32_f16(af[mt], bf[nt], acc[mt][nt], 0, 0, 0);
    }

    #pragma unroll
    for (int mt = 0; mt < 4; ++mt) {
        int ib = i0 + wm * 64 + mt * 16 + q * 4;
        float di[4];
        #pragma unroll
        for (int r = 0; r < 4; ++r) di[r] = dis_of(deg[ib + r]) * out_scale;
        #pragma unroll
        for (int nt = 0; nt < 2; ++nt) {
            int n = n0 + wn * 32 + nt * 16 + lm;
            #pragma unroll
            for (int r = 0; r < 4; ++r) {
                float v = acc[mt][nt][r] * di[r];
                outT[(size_t)n * NND + ib + r] = (_Float16)v;
            }
        }
    }
}

// ------------- big GEMM (2-phase dbuf, single N-pass, conflict-free LDS via source swizzle) ------
// Cp[z][j][n] = sum_{i in z-chunk} Wh[j][i]*Bt[n][i]. Tile 128(M) x BN(N), BK=32,
// 4 waves: wm = M-half, wn = N-half; each wave acc[4][NT] (NT = BN/32).
// LDS linear for global_load_lds; global source chunk pre-permuted, reads XOR back.
template <int BN, int NT, int ZSTEPS>
__global__ __launch_bounds__(256, 2) void k_mm_big(
    const _Float16* __restrict__ Wh, const _Float16* __restrict__ Bt, float* __restrict__ Cp) {

    constexpr int BISS = BN / 64;                 // B gload issues per K-step
    constexpr int ABYT = 128 * 32 * 2;            // A buffer bytes
    constexpr int BBYT = BN * 32 * 2;             // B buffer bytes
    __shared__ __align__(16) _Float16 As[2 * 128 * 32];
    __shared__ __align__(16) _Float16 Bs[2 * BN * 32];

    int t = threadIdx.x;
    int bx = blockIdx.x;
    bx = (bx & 7) * 8 + (bx >> 3);                // XCD-aware swizzle (64 tiles, bijective)
    int j0 = bx * 128;
    size_t i_begin = (size_t)blockIdx.z * (ZSTEPS * 32);
    float* C = Cp + (size_t)blockIdx.z * (size_t)NND * BN;

    int lane = t & 63, w = t >> 6;
    int wm = w & 1, wn = w >> 1;
    int lm = lane & 15, q = lane >> 4;
    int qa = q ^ ((lm >> 1) & 3);                 // swizzled 16B-chunk for LDS reads

    // staging: lane -> (row = u*16 + (lane>>2), slot-chunk = lane&3);
    // global chunk fetched = slot-chunk ^ ((row>>1)&3) = (lane&3) ^ ((lane>>3)&3)
    int srow = lane >> 2;
    int scol = ((lane & 3) ^ ((lane >> 3) & 3)) * 8;
    const _Float16* aS = Wh + (size_t)(j0 + w * 16 + srow) * NND + i_begin + scol;
    const _Float16* bS = Bt + (size_t)(w * 16 + srow) * NND + i_begin + scol;

    char* aLb = (char*)As + w * 1024;
    char* bLb = (char*)Bs + w * 1024;

    floatx4 acc[4][NT];
    #pragma unroll
    for (int a = 0; a < 4; ++a)
        #pragma unroll
        for (int b = 0; b < NT; ++b) acc[a][b] = (floatx4){0.f, 0.f, 0.f, 0.f};

    // prologue: stage tile 0 into buf 0
    #pragma unroll
    for (int s = 0; s < 2; ++s)    GLOAD16(aS + (size_t)(64 * s) * NND, aLb + s * 4096);
    #pragma unroll
    for (int s = 0; s < BISS; ++s) GLOAD16(bS + (size_t)(64 * s) * NND, bLb + s * 4096);
    VMCNT0();
    __builtin_amdgcn_s_barrier();

    for (int ks = 0; ks < ZSTEPS; ++ks) {
        int cur = ks & 1;
        const _Float16* Ab = As + cur * (128 * 32);
        const _Float16* Bb = Bs + cur * (BN * 32);

        if (ks < ZSTEPS - 1) {                    // prefetch next tile into other buf
            int ko = (ks + 1) * 32;
            char* aL = aLb + (cur ^ 1) * ABYT;
            char* bL = bLb + (cur ^ 1) * BBYT;
            #pragma unroll
            for (int s = 0; s < 2; ++s)    GLOAD16(aS + (size_t)(64 * s) * NND + ko, aL + s * 4096);
            #pragma unroll
            for (int s = 0; s < BISS; ++s) GLOAD16(bS + (size_t)(64 * s) * NND + ko, bL + s * 4096);
        }

        half8 af[4], bf[NT];
        #pragma unroll
        for (int mt = 0; mt < 4; ++mt) {
            int m = wm * 64 + mt * 16 + lm;
            af[mt] = *(const half8*)(&Ab[m * 32 + qa * 8]);
        }
        #pragma unroll
        for (int nt = 0; nt < NT; ++nt) {
            int n = wn * (NT * 16) + nt * 16 + lm;
            bf[nt] = *(const half8*)(&Bb[n * 32 + qa * 8]);
        }
        __builtin_amdgcn_s_setprio(1);
        #pragma unroll
        for (int mt = 0; mt < 4; ++mt)
            #pragma unroll
            for (int nt = 0; nt < NT; ++nt)
                acc[mt][nt] = __builtin_amdgcn_mfma_f32_16x16x32_f16(af[mt], bf[nt], acc[mt][nt], 0, 0, 0);
        __builtin_amdgcn_s_setprio(0);

        VMCNT0();
        __builtin_amdgcn_s_barrier();
    }

    #pragma unroll
    for (int mt = 0; mt < 4; ++mt) {
        int rb = j0 + wm * 64 + mt * 16 + q * 4;
        #pragma unroll
        for (int nt = 0; nt < NT; ++nt) {
            int col = wn * (NT * 16) + nt * 16 + lm;
            #pragma unroll
            for (int r = 0; r < 4; ++r)
                __builtin_nontemporal_store(acc[mt][nt][r], &C[(size_t)(rb + r) * BN + col]);
        }
    }
}

// ------------- epilogue: reduce NZ z-partials; out = f16( (dis_j*S/1024 + bias[n]) [relu] * 64 ) ----
template <int NSH, bool RELU, int NZ>
__global__ __launch_bounds__(256) void k_finalize(const float* __restrict__ Cp, const float* __restrict__ deg,
                                                  const float* __restrict__ bias, _Float16* __restrict__ out) {
    int idx4 = (blockIdx.x * 256 + threadIdx.x) * 4;
    f4v v = {0.f, 0.f, 0.f, 0.f};
    #pragma unroll
    for (int z = 0; z < NZ; ++z) {
        f4v p = __builtin_nontemporal_load((const f4v*)(Cp + (size_t)z * (NND << NSH) + idx4));
        #pragma unroll
        for (int r = 0; r < 4; ++r) v[r] += p[r];
    }
    int j  = idx4 >> NSH;
    int n0 = idx4 & ((1 << NSH) - 1);
    float dj = dis_of(deg[j]) * (1.f / 1024.f);
    f4v b4 = *(const f4v*)(bias + n0);
    half4v o;
    #pragma unroll
    for (int r = 0; r < 4; ++r) {
        float x = v[r] * dj + b4[r];
        if (RELU) x = fmaxf(x, 0.f);
        o[r] = (_Float16)(x * 64.f);
    }
    *(half4v*)(out + idx4) = o;
}

// ------------- edge scores: 16 lanes/edge, 4 edges/group batched for MLP; zh rows are 256B -------
// eidx/out streams are non-temporal so the 2MB zh gather table stays L2-resident.
__global__ __launch_bounds__(256) void k_edges(const _Float16* __restrict__ zh, const int* __restrict__ ei,
                                               float* __restrict__ out, int npred) {
    int g0 = ((blockIdx.x * 256 + threadIdx.x) >> 4) * 4;
    int l = threadIdx.x & 15;
    if (g0 >= npred) return;
    int a[4], b[4];
    #pragma unroll
    for (int e = 0; e < 4; ++e) {
        a[e] = __builtin_nontemporal_load(ei + g0 + e);
        b[e] = __builtin_nontemporal_load(ei + npred + g0 + e);
    }
    half8 za[4], zb[4];
    #pragma unroll
    for (int e = 0; e < 4; ++e) {
        za[e] = *(const half8*)(zh + (size_t)a[e] * 128 + l * 8);
        zb[e] = *(const half8*)(zh + (size_t)b[e] * 128 + l * 8);
    }
    #pragma unroll
    for (int e = 0; e < 4; ++e) {
        float s = 0.f;
        #pragma unroll
        for (int u = 0; u < 4; ++u) {
            half2v a2 = {za[e][2 * u], za[e][2 * u + 1]};
            half2v b2 = {zb[e][2 * u], zb[e][2 * u + 1]};
            s = __builtin_amdgcn_fdot2(a2, b2, s, false);
        }
        s += __shfl_xor(s, 1);
        s += __shfl_xor(s, 2);
        s += __shfl_xor(s, 4);
        s += __shfl_xor(s, 8);
        if (l == 0) __builtin_nontemporal_store(s * (1.f / 4096.f), out + g0 + e);
    }
}

extern "C" void kernel_launch(void* const* d_in, const int* in_sizes, int n_in,
                              void* d_out, int out_size, void* d_ws, size_t ws_size,
                              hipStream_t stream) {
    const int*   nodes = (const int*)d_in[0];
    const float* attn  = (const float*)d_in[1];
    const int*   eidx  = (const int*)d_in[2];
    const float* emb   = (const float*)d_in[3];
    const float* W1    = (const float*)d_in[4];
    const float* b1    = (const float*)d_in[5];
    const float* W2    = (const float*)d_in[6];
    const float* b2    = (const float*)d_in[7];
    float* out = (float*)d_out;
    int npred = in_sizes[2] / 2;

    char* ws = (char*)d_ws;
    float*    deg = (float*)(ws);                         // 32 KB
    _Float16* Wh  = (_Float16*)(ws + 0x10000);            // 128 MB f16 [8192][8192]
    float*    C1p = (float*)(ws + 0x8010000);             // 64 MB  fp32 z8 x [8192][256]
    float*    C2p = (float*)(ws + 0xC010000);             // 32 MB  fp32 z8 x [8192][128]
    _Float16* M1p = (_Float16*)(ws + 0xE010000);          // 4 MB   f16 [256][8192]
    _Float16* h   = (_Float16*)(ws + 0xE410000);          // 4 MB   f16 [8192][256]
    _Float16* M2p = (_Float16*)(ws + 0xE810000);          // 2 MB   f16 [128][8192]
    _Float16* zh  = (_Float16*)(ws + 0xEA10000);          // 2 MB   f16 [8192][128]

    hipMemsetAsync(deg, 0, 8192 * sizeof(float), stream);

    k_degT<<<dim3(64, 64), 256, 0, stream>>>(attn, Wh, deg);

    // M1p[n][i] = f16(1024 * dis_i * (x@W1)[i,n]);  A staged as 16*x, so out_scale = 64
    k_mm_small<float><<<dim3(64, 4), 256, 0, stream>>>(emb, nodes, W1, 256, M1p, deg, 64.f);
    // GEMM1: single N-pass (NT=8), z=8 chunks of K=1024
    k_mm_big<256, 8, 32><<<dim3(64, 1, 8), 256, 0, stream>>>(Wh, M1p, C1p);
    // h = relu(dis_j*sum(C1p)/1024 + b1) * 64
    k_finalize<8, true, 8><<<2048, 256, 0, stream>>>(C1p, deg, b1, h);
    // M2p[n][i] = f16(1024 * dis_i * (h_true@W2)[i,n]); h is 64*h_true, so out_scale = 16
    k_mm_small<_Float16><<<dim3(64, 2), 256, 0, stream>>>(h, nullptr, W2, 128, M2p, deg, 16.f);
    k_mm_big<128, 4, 32><<<dim3(64, 1, 8), 256, 0, stream>>>(Wh, M2p, C2p);
    // zh = (dis_j*sum(C2p)/1024 + b2) * 64
    k_finalize<7, false, 8><<<1024, 256, 0, stream>>>(C2p, deg, b2, zh);

    k_edges<<<(npred + 63) / 64, 256, 0, stream>>>(zh, eidx, out, npred);
}